// Round 1
// baseline (210.586 us; speedup 1.0000x reference)
//
#include <hip/hip_runtime.h>
#include <math.h>

#define HIDDEN 128
#define HEADS 8
#define HDIM 16
#define NSEQ 512
#define NBATCH 4
#define SPAD 516       // scores LDS row stride (512 + 4): <=2-way conflicts in all phases
#define TK 32          // edge-feature k-tile
#define EFPAD 132      // ef tile row stride (128 + 4): conflict-free bias dot
#define NEGINF (-1e30f)

// ---------------- Kernel 1: fused Q/K/V projection ----------------
// grid: (B*N/8) blocks x 128 threads; each block does 8 rows.
__global__ __launch_bounds__(128) void qkv_proj(
    const float* __restrict__ node,
    const float* __restrict__ Wq, const float* __restrict__ bq,
    const float* __restrict__ Wk, const float* __restrict__ bk,
    const float* __restrict__ Wv, const float* __restrict__ bv,
    float* __restrict__ Q, float* __restrict__ K, float* __restrict__ V)
{
    const int ROWS = 8;
    __shared__ float sX[ROWS][HIDDEN];
    const int row0 = blockIdx.x * ROWS;
    const int tid = threadIdx.x;

    const float4* src = (const float4*)(node + row0 * HIDDEN);
    float4* dst = (float4*)(&sX[0][0]);
    #pragma unroll
    for (int i = 0; i < ROWS * HIDDEN / 4 / 128; i++)
        dst[tid + i * 128] = src[tid + i * 128];
    __syncthreads();

    float accQ[ROWS], accK[ROWS], accV[ROWS];
    #pragma unroll
    for (int r = 0; r < ROWS; r++) { accQ[r] = 0.f; accK[r] = 0.f; accV[r] = 0.f; }
    const int c = tid;
    for (int d = 0; d < HIDDEN; d++) {
        const float wq = Wq[d * HIDDEN + c];
        const float wk = Wk[d * HIDDEN + c];
        const float wv = Wv[d * HIDDEN + c];
        #pragma unroll
        for (int r = 0; r < ROWS; r++) {
            const float x = sX[r][d];
            accQ[r] = fmaf(x, wq, accQ[r]);
            accK[r] = fmaf(x, wk, accK[r]);
            accV[r] = fmaf(x, wv, accV[r]);
        }
    }
    const float bqv = bq[c], bkv = bk[c], bvv = bv[c];
    #pragma unroll
    for (int r = 0; r < ROWS; r++) {
        const int off = (row0 + r) * HIDDEN + c;
        Q[off] = accQ[r] + bqv;
        K[off] = accK[r] + bkv;
        V[off] = accV[r] + bvv;
    }
}

// ---------------- Kernel 2: fused attention (one block per (b,q)) ----------------
__global__ __launch_bounds__(256) void attn_fused(
    const float* __restrict__ ef,     // [B][N][N][HIDDEN]
    const int*   __restrict__ mask,   // [B][N][N]
    const float* __restrict__ We,     // [HIDDEN][HEADS]
    const float* __restrict__ be,     // [HEADS]
    const float* __restrict__ Q,      // [B*N][HIDDEN]
    const float* __restrict__ K,
    const float* __restrict__ V,
    float* __restrict__ attn)         // [B*N][HIDDEN]
{
    __shared__ float sQ[HIDDEN];
    __shared__ float sWe[HIDDEN][HEADS];
    __shared__ float sEf[TK][EFPAD];
    __shared__ float sS[HEADS][SPAD];   // scores -> weights
    __shared__ float sOut[2][HIDDEN];

    const int bq = blockIdx.x;          // b*512 + q
    const int b  = bq >> 9;
    const int tid = threadIdx.x;

    // ---- Phase 0: stage Q row and We ----
    if (tid < HIDDEN) sQ[tid] = Q[bq * HIDDEN + tid];
    #pragma unroll
    for (int i = 0; i < HIDDEN * HEADS / 256; i++)
        ((float*)sWe)[tid + i * 256] = We[tid + i * 256];
    __syncthreads();

    // ---- Phase A: sS[h][k] = scale * dot(Q_h, K[b,k]_h) ----
    {
        const int h = tid & 7;
        const int kbase = tid >> 3;     // 0..31
        float qreg[HDIM];
        #pragma unroll
        for (int i = 0; i < HDIM; i++) qreg[i] = sQ[h * HDIM + i];
        #pragma unroll 2
        for (int kk = 0; kk < 16; kk++) {
            const int k = kbase + kk * 32;
            const float* kp = K + (b * NSEQ + k) * HIDDEN + h * HDIM;
            float acc = 0.f;
            #pragma unroll
            for (int i = 0; i < HDIM; i++) acc = fmaf(qreg[i], kp[i], acc);
            sS[h][k] = acc * 0.25f;     // 1/sqrt(16)
        }
    }

    // ---- Phase B: add edge bias + mask, tiled over k ----
    const float bev = be[tid & 7];
    const float* efbase = ef + (size_t)bq * NSEQ * HIDDEN;
    const int* mbase = mask + (size_t)bq * NSEQ;
    for (int k0 = 0; k0 < NSEQ; k0 += TK) {
        __syncthreads();   // previous tile's compute done (also closes Phase A on first iter)
        // stage TK x 128 floats, coalesced float4
        {
            const float4* gsrc = (const float4*)(efbase + k0 * HIDDEN);
            #pragma unroll
            for (int i = 0; i < TK * HIDDEN / 4 / 256; i++) {
                const int idx = tid + i * 256;
                const int row = idx >> 5;        // /32 float4 per row
                const int c4  = idx & 31;
                *(float4*)(&sEf[row][c4 * 4]) = gsrc[idx];
            }
        }
        __syncthreads();
        // compute: one thread per (kk, h)
        {
            const int kk = tid >> 3;
            const int h  = tid & 7;
            float bias = bev;
            #pragma unroll 4
            for (int d = 0; d < HIDDEN; d++)
                bias = fmaf(sEf[kk][d], sWe[d][h], bias);
            const int k = k0 + kk;
            const float sc = sS[h][k] + bias;
            sS[h][k] = mbase[k] ? sc : NEGINF;
        }
    }
    __syncthreads();

    // ---- Phase C: softmax per head (32 lanes per head, strided k) ----
    {
        const int h = tid >> 5;
        const int j = tid & 31;
        float m = NEGINF;
        #pragma unroll
        for (int i = 0; i < 16; i++) m = fmaxf(m, sS[h][j + 32 * i]);
        #pragma unroll
        for (int off = 16; off >= 1; off >>= 1) m = fmaxf(m, __shfl_xor(m, off, 64));
        float sum = 0.f;
        #pragma unroll
        for (int i = 0; i < 16; i++) {
            const float s = sS[h][j + 32 * i];
            const float e = (s <= -1e29f) ? 0.f : __expf(s - m);
            sum += e;
            sS[h][j + 32 * i] = e;
        }
        #pragma unroll
        for (int off = 16; off >= 1; off >>= 1) sum += __shfl_xor(sum, off, 64);
        const float rinv = (sum > 0.f) ? 1.f / sum : 0.f;
        #pragma unroll
        for (int i = 0; i < 16; i++) sS[h][j + 32 * i] *= rinv;
    }
    __syncthreads();

    // ---- Phase D: out[d] = sum_k w[h][k] * V[b,k,d] ----
    {
        const int d = tid & 127;
        const int half = tid >> 7;
        const int h = d >> 4;
        float acc = 0.f;
        const float* vp = V + (size_t)(b * NSEQ + half * 256) * HIDDEN + d;
        const float* wp = &sS[h][half * 256];
        #pragma unroll 8
        for (int k = 0; k < 256; k++)
            acc = fmaf(wp[k], vp[(size_t)k * HIDDEN], acc);
        sOut[half][d] = acc;
    }
    __syncthreads();
    if (tid < HIDDEN)
        attn[bq * HIDDEN + tid] = sOut[0][tid] + sOut[1][tid];
}

// ---------------- Kernel 3: output projection ----------------
__global__ __launch_bounds__(128) void out_proj(
    const float* __restrict__ attn,
    const float* __restrict__ Wo, const float* __restrict__ bo,
    float* __restrict__ out)
{
    const int ROWS = 8;
    __shared__ float sX[ROWS][HIDDEN];
    const int row0 = blockIdx.x * ROWS;
    const int tid = threadIdx.x;

    const float4* src = (const float4*)(attn + row0 * HIDDEN);
    float4* dst = (float4*)(&sX[0][0]);
    #pragma unroll
    for (int i = 0; i < ROWS * HIDDEN / 4 / 128; i++)
        dst[tid + i * 128] = src[tid + i * 128];
    __syncthreads();

    float acc[ROWS];
    #pragma unroll
    for (int r = 0; r < ROWS; r++) acc[r] = 0.f;
    const int c = tid;
    for (int d = 0; d < HIDDEN; d++) {
        const float w = Wo[d * HIDDEN + c];
        #pragma unroll
        for (int r = 0; r < ROWS; r++)
            acc[r] = fmaf(sX[r][d], w, acc[r]);
    }
    const float bov = bo[c];
    #pragma unroll
    for (int r = 0; r < ROWS; r++)
        out[(row0 + r) * HIDDEN + c] = acc[r] + bov;
}

extern "C" void kernel_launch(void* const* d_in, const int* in_sizes, int n_in,
                              void* d_out, int out_size, void* d_ws, size_t ws_size,
                              hipStream_t stream) {
    const float* node = (const float*)d_in[0];
    const float* ef   = (const float*)d_in[1];
    const int*   mask = (const int*)d_in[2];
    const float* Wq = (const float*)d_in[3];
    const float* bq = (const float*)d_in[4];
    const float* Wk = (const float*)d_in[5];
    const float* bk = (const float*)d_in[6];
    const float* Wv = (const float*)d_in[7];
    const float* bv = (const float*)d_in[8];
    const float* We = (const float*)d_in[9];
    const float* be = (const float*)d_in[10];
    const float* Wo = (const float*)d_in[11];
    const float* bo = (const float*)d_in[12];
    float* out = (float*)d_out;

    const int ROWS_TOT = NBATCH * NSEQ;              // 2048
    const int RC = ROWS_TOT * HIDDEN;                // 262144 floats
    float* Q = (float*)d_ws;
    float* K = Q + RC;
    float* V = K + RC;
    float* attn = V + RC;

    qkv_proj<<<ROWS_TOT / 8, 128, 0, stream>>>(node, Wq, bq, Wk, bk, Wv, bv, Q, K, V);
    attn_fused<<<ROWS_TOT, 256, 0, stream>>>(ef, mask, We, be, Q, K, V, attn);
    out_proj<<<ROWS_TOT / 8, 128, 0, stream>>>(attn, Wo, bo, out);
}

// Round 3
// 181.272 us; speedup vs baseline: 1.1617x; 1.1617x over previous
//
#include <hip/hip_runtime.h>
#include <math.h>

#define HIDDEN 128
#define HEADS 8
#define HDIM 16
#define NSEQ 512
#define NBATCH 4
#define SPAD 516        // sS row stride: <=2-way banks in all phases
#define PSTRIDE 260     // per-g stride in sP (8*32 rows + pad): 2-way banks
#define PBUF 2080       // 8 * PSTRIDE
#define NEGINF (-1e30f)

// DPP quad-perm fold (VALU, not LDS): v += lane-swapped v. CTRL must be an
// immediate -> template parameter (runtime arg fails to compile).
template <int CTRL>
__device__ __forceinline__ float dpp_xadd(float v) {
    int s = __builtin_amdgcn_update_dpp(0, __float_as_int(v), CTRL, 0xF, 0xF, true);
    return v + __int_as_float(s);
}
#define DPP_XOR1 0xB1   // quad_perm [1,0,3,2]
#define DPP_XOR2 0x4E   // quad_perm [2,3,0,1]

// ---------------- Kernel 1: fused Q/K/V projection ----------------
__global__ __launch_bounds__(128) void qkv_proj(
    const float* __restrict__ node,
    const float* __restrict__ Wq, const float* __restrict__ bq,
    const float* __restrict__ Wk, const float* __restrict__ bk,
    const float* __restrict__ Wv, const float* __restrict__ bv,
    float* __restrict__ Q, float* __restrict__ K, float* __restrict__ V)
{
    const int ROWS = 8;
    __shared__ float sX[ROWS][HIDDEN];
    const int row0 = blockIdx.x * ROWS;
    const int tid = threadIdx.x;

    const float4* src = (const float4*)(node + row0 * HIDDEN);
    float4* dst = (float4*)(&sX[0][0]);
    #pragma unroll
    for (int i = 0; i < ROWS * HIDDEN / 4 / 128; i++)
        dst[tid + i * 128] = src[tid + i * 128];
    __syncthreads();

    float accQ[ROWS], accK[ROWS], accV[ROWS];
    #pragma unroll
    for (int r = 0; r < ROWS; r++) { accQ[r] = 0.f; accK[r] = 0.f; accV[r] = 0.f; }
    const int c = tid;
    for (int d = 0; d < HIDDEN; d++) {
        const float wq = Wq[d * HIDDEN + c];
        const float wk = Wk[d * HIDDEN + c];
        const float wv = Wv[d * HIDDEN + c];
        #pragma unroll
        for (int r = 0; r < ROWS; r++) {
            const float x = sX[r][d];
            accQ[r] = fmaf(x, wq, accQ[r]);
            accK[r] = fmaf(x, wk, accK[r]);
            accV[r] = fmaf(x, wv, accV[r]);
        }
    }
    const float bqv = bq[c], bkv = bk[c], bvv = bv[c];
    #pragma unroll
    for (int r = 0; r < ROWS; r++) {
        const int off = (row0 + r) * HIDDEN + c;
        Q[off] = accQ[r] + bqv;
        K[off] = accK[r] + bkv;
        V[off] = accV[r] + bvv;
    }
}

// ---------------- Kernel 2: fused attention (one block per (b,q)) ----------------
__global__ __launch_bounds__(256, 3) void attn_fused(
    const float* __restrict__ ef,     // [B][N][N][HIDDEN]
    const int*   __restrict__ mask,   // [B][N][N]
    const float* __restrict__ We,     // [HIDDEN][HEADS]
    const float* __restrict__ be,     // [HEADS]
    const float* __restrict__ Q, const float* __restrict__ K,
    const float* __restrict__ V,
    float* __restrict__ attn)         // [B*N][HIDDEN]
{
    __shared__ float sS[HEADS][SPAD];   // scores -> weights
    __shared__ float sP[2 * PBUF];      // partial-bias buffers; reused for PV partials
    __shared__ float sQ[HIDDEN];

    const int bq = blockIdx.x;          // b*512 + q
    const int b  = bq >> 9;
    const int tid = threadIdx.x;
    const int c4 = tid & 31;            // d-chunk: d = 4*c4 .. 4*c4+3
    const int rg = tid >> 5;            // row group: rows rg+8i

    // --- per-thread We chunk in registers: rWe[j][h] = We[(4*c4+j)][h] ---
    float rWe[4][8];
    #pragma unroll
    for (int j = 0; j < 4; j++) {
        const float4* wp = (const float4*)(We + (4 * c4 + j) * 8);
        const float4 a = wp[0], bb = wp[1];
        rWe[j][0] = a.x; rWe[j][1] = a.y; rWe[j][2] = a.z; rWe[j][3] = a.w;
        rWe[j][4] = bb.x; rWe[j][5] = bb.y; rWe[j][6] = bb.z; rWe[j][7] = bb.w;
    }
    if (tid < HIDDEN) sQ[tid] = Q[bq * HIDDEN + tid];

    // --- prefetch ef tile 0 into registers (coalesced: 1KB/instr) ---
    const float4* efb = (const float4*)(ef + (size_t)bq * NSEQ * HIDDEN);
    float4 cur0 = efb[tid], cur1 = efb[tid + 256], cur2 = efb[tid + 512], cur3 = efb[tid + 768];

    __syncthreads();    // sQ ready

    // ---- Phase A: sS[h][k] = scale * dot(Q_h, K[b,k]_h) ----
    {
        const int h = tid & 7;
        const int kbase = tid >> 3;
        float qreg[HDIM];
        #pragma unroll
        for (int i = 0; i < HDIM; i++) qreg[i] = sQ[h * HDIM + i];
        for (int kk = 0; kk < 16; kk++) {
            const int k = kbase + kk * 32;
            const float4* kp = (const float4*)(K + (size_t)(b * NSEQ + k) * HIDDEN + h * HDIM);
            const float4 k0 = kp[0], k1 = kp[1], k2 = kp[2], k3 = kp[3];
            float acc = qreg[0]*k0.x + qreg[1]*k0.y + qreg[2]*k0.z + qreg[3]*k0.w;
            acc = fmaf(qreg[4], k1.x, acc); acc = fmaf(qreg[5], k1.y, acc);
            acc = fmaf(qreg[6], k1.z, acc); acc = fmaf(qreg[7], k1.w, acc);
            acc = fmaf(qreg[8], k2.x, acc); acc = fmaf(qreg[9], k2.y, acc);
            acc = fmaf(qreg[10], k2.z, acc); acc = fmaf(qreg[11], k2.w, acc);
            acc = fmaf(qreg[12], k3.x, acc); acc = fmaf(qreg[13], k3.y, acc);
            acc = fmaf(qreg[14], k3.z, acc); acc = fmaf(qreg[15], k3.w, acc);
            sS[h][k] = acc * 0.25f;     // 1/sqrt(16)
        }
    }

    // ---- Phase B: bias + mask, tiled over k (16 tiles of 32 rows) ----
    const int rrow = tid >> 3, rh = tid & 7;     // reducer role
    const float beh = be[rh];
    const int* mbase = mask + (size_t)bq * NSEQ;
    int mcur = mbase[rrow];                      // mask prefetch (tile 0)
    int buf = 0;

    for (int t = 0; t < 16; t++) {
        // prefetch next tile (ef + mask) while computing this one
        float4 n0, n1, n2, n3; int mnext = 0;
        if (t < 15) {
            const int o = (t + 1) * 1024 + tid;
            n0 = efb[o]; n1 = efb[o + 256]; n2 = efb[o + 512]; n3 = efb[o + 768];
            mnext = mbase[(t + 1) * 32 + rrow];
        }

        // partial bias: rows rg+8i, d-chunk 4*c4..4*c4+3, all 8 heads
        float pb[4][8];
        #pragma unroll
        for (int h = 0; h < 8; h++) {
            pb[0][h] = fmaf(cur0.w, rWe[3][h], fmaf(cur0.z, rWe[2][h], fmaf(cur0.y, rWe[1][h], cur0.x * rWe[0][h])));
            pb[1][h] = fmaf(cur1.w, rWe[3][h], fmaf(cur1.z, rWe[2][h], fmaf(cur1.y, rWe[1][h], cur1.x * rWe[0][h])));
            pb[2][h] = fmaf(cur2.w, rWe[3][h], fmaf(cur2.z, rWe[2][h], fmaf(cur2.y, rWe[1][h], cur2.x * rWe[0][h])));
            pb[3][h] = fmaf(cur3.w, rWe[3][h], fmaf(cur3.z, rWe[2][h], fmaf(cur3.y, rWe[1][h], cur3.x * rWe[0][h])));
        }
        // DPP quad fold: each quad of c4 lanes sums -> 16-d-chunk partials
        #pragma unroll
        for (int i = 0; i < 4; i++)
            #pragma unroll
            for (int h = 0; h < 8; h++)
                pb[i][h] = dpp_xadd<DPP_XOR2>(dpp_xadd<DPP_XOR1>(pb[i][h]));

        // quad leaders store: sP[buf][g][row][h], g = c4>>2 (d 16g..16g+15)
        if ((c4 & 3) == 0) {
            const int g = c4 >> 2;
            #pragma unroll
            for (int i = 0; i < 4; i++) {
                float* p = &sP[buf * PBUF + g * PSTRIDE + (rg + 8 * i) * 8];
                *(float4*)(p)     = make_float4(pb[i][0], pb[i][1], pb[i][2], pb[i][3]);
                *(float4*)(p + 4) = make_float4(pb[i][4], pb[i][5], pb[i][6], pb[i][7]);
            }
        }
        __syncthreads();

        // reducer: one thread per (row, h) sums the 8 g-partials
        {
            const int k = t * 32 + rrow;
            float s = 0.f;
            #pragma unroll
            for (int g = 0; g < 8; g++)
                s += sP[buf * PBUF + g * PSTRIDE + rrow * 8 + rh];
            const float sc = sS[rh][k] + s + beh;
            sS[rh][k] = mcur ? sc : NEGINF;
        }
        buf ^= 1;
        if (t < 15) { cur0 = n0; cur1 = n1; cur2 = n2; cur3 = n3; mcur = mnext; }
    }
    __syncthreads();

    // ---- Phase C: softmax per head (32 lanes per head) ----
    {
        const int h = tid >> 5;
        const int j = tid & 31;
        float m = NEGINF;
        #pragma unroll
        for (int i = 0; i < 16; i++) m = fmaxf(m, sS[h][j + 32 * i]);
        #pragma unroll
        for (int off = 16; off >= 1; off >>= 1) m = fmaxf(m, __shfl_xor(m, off, 64));
        float sum = 0.f;
        #pragma unroll
        for (int i = 0; i < 16; i++) {
            const float s = sS[h][j + 32 * i];
            const float e = (s <= -1e29f) ? 0.f : __expf(s - m);
            sum += e;
            sS[h][j + 32 * i] = e;
        }
        #pragma unroll
        for (int off = 16; off >= 1; off >>= 1) sum += __shfl_xor(sum, off, 64);
        const float rinv = (sum > 0.f) ? 1.f / sum : 0.f;
        #pragma unroll
        for (int i = 0; i < 16; i++) sS[h][j + 32 * i] *= rinv;
    }
    __syncthreads();

    // ---- Phase D: out[d] = sum_k w[h][k] * V[b,k,d]  (float4 over d) ----
    {
        const int d4 = tid & 31;            // d = 4*d4
        const int kg = tid >> 5;            // k group: 64 k's
        const int h = d4 >> 2;              // (4*d4)>>4
        const float4* v4 = (const float4*)(V + (size_t)b * NSEQ * HIDDEN) + d4;
        float4 acc = make_float4(0.f, 0.f, 0.f, 0.f);
        const int k0 = kg * 64;
        #pragma unroll 4
        for (int k = k0; k < k0 + 64; k++) {
            const float w = sS[h][k];
            const float4 vv = v4[(size_t)k * 32];
            acc.x = fmaf(w, vv.x, acc.x);
            acc.y = fmaf(w, vv.y, acc.y);
            acc.z = fmaf(w, vv.z, acc.z);
            acc.w = fmaf(w, vv.w, acc.w);
        }
        *(float4*)(&sP[kg * 132 + d4 * 4]) = acc;   // reuse sP as [8][132]
    }
    __syncthreads();
    if (tid < HIDDEN) {
        float s = 0.f;
        #pragma unroll
        for (int g = 0; g < 8; g++) s += sP[g * 132 + tid];
        attn[bq * HIDDEN + tid] = s;
    }
}

// ---------------- Kernel 3: output projection ----------------
__global__ __launch_bounds__(128) void out_proj(
    const float* __restrict__ attn,
    const float* __restrict__ Wo, const float* __restrict__ bo,
    float* __restrict__ out)
{
    const int ROWS = 8;
    __shared__ float sX[ROWS][HIDDEN];
    const int row0 = blockIdx.x * ROWS;
    const int tid = threadIdx.x;

    const float4* src = (const float4*)(attn + row0 * HIDDEN);
    float4* dst = (float4*)(&sX[0][0]);
    #pragma unroll
    for (int i = 0; i < ROWS * HIDDEN / 4 / 128; i++)
        dst[tid + i * 128] = src[tid + i * 128];
    __syncthreads();

    float acc[ROWS];
    #pragma unroll
    for (int r = 0; r < ROWS; r++) acc[r] = 0.f;
    const int c = tid;
    for (int d = 0; d < HIDDEN; d++) {
        const float w = Wo[d * HIDDEN + c];
        #pragma unroll
        for (int r = 0; r < ROWS; r++)
            acc[r] = fmaf(sX[r][d], w, acc[r]);
    }
    const float bov = bo[c];
    #pragma unroll
    for (int r = 0; r < ROWS; r++)
        out[(row0 + r) * HIDDEN + c] = acc[r] + bov;
}

extern "C" void kernel_launch(void* const* d_in, const int* in_sizes, int n_in,
                              void* d_out, int out_size, void* d_ws, size_t ws_size,
                              hipStream_t stream) {
    const float* node = (const float*)d_in[0];
    const float* ef   = (const float*)d_in[1];
    const int*   mask = (const int*)d_in[2];
    const float* Wq = (const float*)d_in[3];
    const float* bq = (const float*)d_in[4];
    const float* Wk = (const float*)d_in[5];
    const float* bk = (const float*)d_in[6];
    const float* Wv = (const float*)d_in[7];
    const float* bv = (const float*)d_in[8];
    const float* We = (const float*)d_in[9];
    const float* be = (const float*)d_in[10];
    const float* Wo = (const float*)d_in[11];
    const float* bo = (const float*)d_in[12];
    float* out = (float*)d_out;

    const int ROWS_TOT = NBATCH * NSEQ;              // 2048
    const int RC = ROWS_TOT * HIDDEN;                // 262144 floats
    float* Q = (float*)d_ws;
    float* K = Q + RC;
    float* V = K + RC;
    float* attn = V + RC;

    qkv_proj<<<ROWS_TOT / 8, 128, 0, stream>>>(node, Wq, bq, Wk, bk, Wv, bv, Q, K, V);
    attn_fused<<<ROWS_TOT, 256, 0, stream>>>(ef, mask, We, be, Q, K, V, attn);
    out_proj<<<ROWS_TOT / 8, 128, 0, stream>>>(attn, Wo, bo, out);
}